// Round 1
// baseline (805.611 us; speedup 1.0000x reference)
//
#include <hip/hip_runtime.h>
#include <cmath>

#define D 128
#define NCLS 40

// ---------------- degree / norm ----------------
__global__ __launch_bounds__(256) void set_ones(float* __restrict__ p, int n) {
  int i = blockIdx.x * 256 + threadIdx.x;
  if (i < n) p[i] = 1.0f;  // self-loop contributes 1 to every degree
}

__global__ __launch_bounds__(256) void deg_count(const int* __restrict__ dst, float* __restrict__ deg, int E) {
  int e = blockIdx.x * 256 + threadIdx.x;
  if (e < E) unsafeAtomicAdd(&deg[dst[e]], 1.0f);
}

__global__ __launch_bounds__(256) void to_rsqrt(float* __restrict__ p, int n) {
  int i = blockIdx.x * 256 + threadIdx.x;
  if (i < n) p[i] = rsqrtf(p[i]);  // deg >= 1 always (self-loop)
}

// ---------------- GEMM: C[N,128] = A[N,128] @ B[128,128] ----------------
// 32-row tile, B staged in 64-row k-chunks. LDS = 50,688 B -> 3 blocks/CU.
__global__ __launch_bounds__(256) void gemm128(const float* __restrict__ A, const float* __restrict__ B,
                                               float* __restrict__ C, int N) {
  __shared__ float Bs[64][132];
  __shared__ float As[32][132];
  const int tid = threadIdx.x;
  const int row0 = blockIdx.x * 32;

  // Load A tile (32 rows x 128) as float4 (coalesced)
  for (int i = tid; i < 32 * 32; i += 256) {
    int r = i >> 5;
    int c = (i & 31) << 2;
    int gr = row0 + r;
    float4 v = make_float4(0.f, 0.f, 0.f, 0.f);
    if (gr < N) v = *(const float4*)(A + (size_t)gr * D + c);
    As[r][c] = v.x; As[r][c + 1] = v.y; As[r][c + 2] = v.z; As[r][c + 3] = v.w;
  }

  const int tx = tid & 15;   // 16 col-groups of 8 cols
  const int ty = tid >> 4;   // 16 row-groups of 2 rows
  const int r0 = ty * 2;
  const int c0 = tx * 8;
  float acc[2][8];
#pragma unroll
  for (int i = 0; i < 2; ++i)
#pragma unroll
    for (int j = 0; j < 8; ++j) acc[i][j] = 0.f;

  for (int kc = 0; kc < 128; kc += 64) {
    // stage B rows kc..kc+63
    for (int i = tid; i < 64 * 32; i += 256) {
      int r = i >> 5;
      int c = (i & 31) << 2;
      float4 v = *(const float4*)(B + (kc + r) * D + c);
      Bs[r][c] = v.x; Bs[r][c + 1] = v.y; Bs[r][c + 2] = v.z; Bs[r][c + 3] = v.w;
    }
    __syncthreads();
#pragma unroll 8
    for (int k = 0; k < 64; ++k) {
      float a0 = As[r0][kc + k];
      float a1 = As[r0 + 1][kc + k];
      float4 b0 = *(const float4*)&Bs[k][c0];
      float4 b1 = *(const float4*)&Bs[k][c0 + 4];
      acc[0][0] += a0 * b0.x; acc[0][1] += a0 * b0.y; acc[0][2] += a0 * b0.z; acc[0][3] += a0 * b0.w;
      acc[0][4] += a0 * b1.x; acc[0][5] += a0 * b1.y; acc[0][6] += a0 * b1.z; acc[0][7] += a0 * b1.w;
      acc[1][0] += a1 * b0.x; acc[1][1] += a1 * b0.y; acc[1][2] += a1 * b0.z; acc[1][3] += a1 * b0.w;
      acc[1][4] += a1 * b1.x; acc[1][5] += a1 * b1.y; acc[1][6] += a1 * b1.z; acc[1][7] += a1 * b1.w;
    }
    __syncthreads();
  }

#pragma unroll
  for (int i = 0; i < 2; ++i) {
    int gr = row0 + r0 + i;
    if (gr < N) {
      float4 v0 = make_float4(acc[i][0], acc[i][1], acc[i][2], acc[i][3]);
      float4 v1 = make_float4(acc[i][4], acc[i][5], acc[i][6], acc[i][7]);
      *(float4*)(C + (size_t)gr * D + c0) = v0;
      *(float4*)(C + (size_t)gr * D + c0 + 4) = v1;
    }
  }
}

// ---------------- propagate ----------------
// h[i,:] = t[i,:] * dinv[i]^2   (self-loop term, also initializes h)
__global__ __launch_bounds__(256) void self_init(const float* __restrict__ t, const float* __restrict__ dinv,
                                                 float* __restrict__ h, int total) {
  int i = blockIdx.x * 256 + threadIdx.x;
  if (i < total) {
    float dv = dinv[i >> 7];
    h[i] = t[i] * dv * dv;
  }
}

// h[dst,:] += dinv[src]*dinv[dst] * t[src,:]  -- 2 edges per 256-thread block
__global__ __launch_bounds__(256) void scatter_edges(const int* __restrict__ src, const int* __restrict__ dst,
                                                     const float* __restrict__ dinv, const float* __restrict__ t,
                                                     float* __restrict__ h, int E) {
  int e = blockIdx.x * 2 + (threadIdx.x >> 7);
  if (e >= E) return;
  int f = threadIdx.x & (D - 1);
  int s = src[e], d = dst[e];
  float nrm = dinv[s] * dinv[d];
  unsafeAtomicAdd(&h[(size_t)d * D + f], nrm * t[(size_t)s * D + f]);
}

__global__ __launch_bounds__(256) void bias_tanh(float* __restrict__ h, const float* __restrict__ b, int total) {
  int i = blockIdx.x * 256 + threadIdx.x;
  if (i < total) h[i] = tanhf(h[i] + b[i & (D - 1)]);
}

// ---------------- head: out[N,40] = H[N,128] @ W[128,40] + b ----------------
__global__ __launch_bounds__(640) void linhead(const float* __restrict__ H, const float* __restrict__ W,
                                               const float* __restrict__ bias, float* __restrict__ out, int N) {
  __shared__ float Ws[D * NCLS];   // 20,480 B
  __shared__ float Hs[16][D];      //  8,192 B
  const int tid = threadIdx.x;
  for (int i = tid; i < D * NCLS; i += 640) Ws[i] = W[i];
  const int row0 = blockIdx.x * 16;
  for (int i = tid; i < 16 * D; i += 640) {
    int r = i >> 7, c = i & (D - 1);
    int gr = row0 + r;
    Hs[r][c] = (gr < N) ? H[(size_t)gr * D + c] : 0.f;
  }
  __syncthreads();
  const int c = tid % NCLS;
  const int r = tid / NCLS;  // 0..15
  float acc = bias[c];
#pragma unroll 8
  for (int k = 0; k < D; ++k) acc += Hs[r][k] * Ws[k * NCLS + c];
  int gr = row0 + r;
  if (gr < N) out[(size_t)gr * NCLS + c] = acc;
}

extern "C" void kernel_launch(void* const* d_in, const int* in_sizes, int n_in,
                              void* d_out, int out_size, void* d_ws, size_t ws_size,
                              hipStream_t stream) {
  const float* x    = (const float*)d_in[0];
  const int*   ei   = (const int*)d_in[1];   // [2, E] int32
  const float* W1   = (const float*)d_in[2];
  const float* b1   = (const float*)d_in[3];
  const float* W2   = (const float*)d_in[4];
  const float* b2   = (const float*)d_in[5];
  const float* Wlin = (const float*)d_in[6];
  const float* blin = (const float*)d_in[7];
  float* out = (float*)d_out;

  const int N = in_sizes[0] / D;   // 50000
  const int E = in_sizes[1] / 2;   // 600000
  const int* srcp = ei;
  const int* dstp = ei + E;

  // workspace layout: dinv | t | h   (~51.5 MB)
  char* ws = (char*)d_ws;
  float* dinv = (float*)ws;
  float* t    = (float*)(ws + 262144);
  float* h    = (float*)(ws + 262144 + (size_t)N * D * sizeof(float));

  const int total = N * D;
  dim3 b256(256);

  // degree -> dinv (self-loop included via init=1)
  set_ones<<<(N + 255) / 256, b256, 0, stream>>>(dinv, N);
  deg_count<<<(E + 255) / 256, b256, 0, stream>>>(dstp, dinv, E);
  to_rsqrt<<<(N + 255) / 256, b256, 0, stream>>>(dinv, N);

  // layer 1
  gemm128<<<(N + 31) / 32, b256, 0, stream>>>(x, W1, t, N);
  self_init<<<(total + 255) / 256, b256, 0, stream>>>(t, dinv, h, total);
  scatter_edges<<<(E + 1) / 2, b256, 0, stream>>>(srcp, dstp, dinv, t, h, E);
  bias_tanh<<<(total + 255) / 256, b256, 0, stream>>>(h, b1, total);

  // layer 2
  gemm128<<<(N + 31) / 32, b256, 0, stream>>>(h, W2, t, N);
  self_init<<<(total + 255) / 256, b256, 0, stream>>>(t, dinv, h, total);
  scatter_edges<<<(E + 1) / 2, b256, 0, stream>>>(srcp, dstp, dinv, t, h, E);
  bias_tanh<<<(total + 255) / 256, b256, 0, stream>>>(h, b2, total);

  // head
  linhead<<<(N + 15) / 16, dim3(640), 0, stream>>>(h, Wlin, blin, out, N);
}

// Round 2
// 453.477 us; speedup vs baseline: 1.7765x; 1.7765x over previous
//
#include <hip/hip_runtime.h>
#include <cmath>

#define D 128
#define NCLS 40

struct __align__(8) Edge { int s; float w; };

// ---------------- degree ----------------
__global__ __launch_bounds__(256) void deg_count_int(const int* __restrict__ dst, int* __restrict__ deg, int E) {
  int e = blockIdx.x * 256 + threadIdx.x;
  if (e < E) atomicAdd(&deg[dst[e]], 1);
}

__global__ __launch_bounds__(256) void dinv_kernel(const int* __restrict__ deg, float* __restrict__ dinv, int n) {
  int i = blockIdx.x * 256 + threadIdx.x;
  if (i < n) dinv[i] = rsqrtf((float)deg[i] + 1.0f);  // +1 = self-loop
}

// ---------------- single-block exclusive scan over n ints ----------------
__global__ __launch_bounds__(1024) void scan_rowptr(const int* __restrict__ deg, int* __restrict__ row_ptr, int n) {
  __shared__ int wsum[16];
  __shared__ int blocktot;
  const int lane = threadIdx.x & 63;
  const int wid = threadIdx.x >> 6;
  int carry = 0;
  for (int base = 0; base < n; base += 1024) {
    int i = base + threadIdx.x;
    int v = (i < n) ? deg[i] : 0;
    // inclusive wave scan
    int x = v;
#pragma unroll
    for (int off = 1; off < 64; off <<= 1) {
      int y = __shfl_up(x, off, 64);
      if (lane >= off) x += y;
    }
    if (lane == 63) wsum[wid] = x;
    __syncthreads();
    if (wid == 0) {
      int w = (lane < 16) ? wsum[lane] : 0;
      int xx = w;
#pragma unroll
      for (int off = 1; off < 16; off <<= 1) {
        int y = __shfl_up(xx, off, 64);
        if (lane >= off) xx += y;
      }
      if (lane < 16) wsum[lane] = xx - w;  // exclusive wave offset
      if (lane == 15) blocktot = xx;       // block total
    }
    __syncthreads();
    if (i < n) row_ptr[i] = carry + wsum[wid] + (x - v);
    carry += blocktot;
    __syncthreads();  // protect wsum/blocktot for next iteration
  }
  if (threadIdx.x == 0) row_ptr[n] = carry;
}

// ---------------- CSR fill (cursor pre-initialized to row_ptr) ----------------
__global__ __launch_bounds__(256) void fill_csr(const int* __restrict__ src, const int* __restrict__ dst,
                                                const float* __restrict__ dinv, int* __restrict__ cursor,
                                                Edge* __restrict__ csr, int E) {
  int e = blockIdx.x * 256 + threadIdx.x;
  if (e < E) {
    int s = src[e], d = dst[e];
    int pos = atomicAdd(&cursor[d], 1);
    Edge ed; ed.s = s; ed.w = dinv[s] * dinv[d];
    csr[pos] = ed;
  }
}

// ---------------- fused propagate: one wave per node ----------------
// out[i,:] = tanh( dinv[i]^2 * t[i,:] + sum_e w_e * t[src_e,:] + b )
__global__ __launch_bounds__(256) void gather_fused(const float* __restrict__ t, const int* __restrict__ row_ptr,
                                                    const Edge* __restrict__ csr, const float* __restrict__ dinv,
                                                    const float* __restrict__ bias, float* __restrict__ out, int N) {
  int node = blockIdx.x * 4 + (threadIdx.x >> 6);
  if (node >= N) return;
  int lane = threadIdx.x & 63;
  const float* trow = t + (size_t)node * D + lane * 2;
  float dv = dinv[node];
  float2 tv = *(const float2*)trow;
  float2 acc;
  acc.x = dv * dv * tv.x;
  acc.y = dv * dv * tv.y;
  int beg = row_ptr[node], end = row_ptr[node + 1];
  for (int e = beg; e < end; ++e) {
    Edge ed = csr[e];  // same addr across wave -> broadcast
    float2 sv = *(const float2*)(t + (size_t)ed.s * D + lane * 2);
    acc.x += ed.w * sv.x;
    acc.y += ed.w * sv.y;
  }
  float2 bv = *(const float2*)(bias + lane * 2);
  acc.x = tanhf(acc.x + bv.x);
  acc.y = tanhf(acc.y + bv.y);
  *(float2*)(out + (size_t)node * D + lane * 2) = acc;
}

// ---------------- GEMM: C[N,128] = A[N,128] @ B[128,128] ----------------
__global__ __launch_bounds__(256) void gemm128(const float* __restrict__ A, const float* __restrict__ B,
                                               float* __restrict__ C, int N) {
  __shared__ float Bs[64][132];
  __shared__ float As[32][132];
  const int tid = threadIdx.x;
  const int row0 = blockIdx.x * 32;

  for (int i = tid; i < 32 * 32; i += 256) {
    int r = i >> 5;
    int c = (i & 31) << 2;
    int gr = row0 + r;
    float4 v = make_float4(0.f, 0.f, 0.f, 0.f);
    if (gr < N) v = *(const float4*)(A + (size_t)gr * D + c);
    As[r][c] = v.x; As[r][c + 1] = v.y; As[r][c + 2] = v.z; As[r][c + 3] = v.w;
  }

  const int tx = tid & 15;
  const int ty = tid >> 4;
  const int r0 = ty * 2;
  const int c0 = tx * 8;
  float acc[2][8];
#pragma unroll
  for (int i = 0; i < 2; ++i)
#pragma unroll
    for (int j = 0; j < 8; ++j) acc[i][j] = 0.f;

  for (int kc = 0; kc < 128; kc += 64) {
    for (int i = tid; i < 64 * 32; i += 256) {
      int r = i >> 5;
      int c = (i & 31) << 2;
      float4 v = *(const float4*)(B + (kc + r) * D + c);
      Bs[r][c] = v.x; Bs[r][c + 1] = v.y; Bs[r][c + 2] = v.z; Bs[r][c + 3] = v.w;
    }
    __syncthreads();
#pragma unroll 8
    for (int k = 0; k < 64; ++k) {
      float a0 = As[r0][kc + k];
      float a1 = As[r0 + 1][kc + k];
      float4 b0 = *(const float4*)&Bs[k][c0];
      float4 b1 = *(const float4*)&Bs[k][c0 + 4];
      acc[0][0] += a0 * b0.x; acc[0][1] += a0 * b0.y; acc[0][2] += a0 * b0.z; acc[0][3] += a0 * b0.w;
      acc[0][4] += a0 * b1.x; acc[0][5] += a0 * b1.y; acc[0][6] += a0 * b1.z; acc[0][7] += a0 * b1.w;
      acc[1][0] += a1 * b0.x; acc[1][1] += a1 * b0.y; acc[1][2] += a1 * b0.z; acc[1][3] += a1 * b0.w;
      acc[1][4] += a1 * b1.x; acc[1][5] += a1 * b1.y; acc[1][6] += a1 * b1.z; acc[1][7] += a1 * b1.w;
    }
    __syncthreads();
  }

#pragma unroll
  for (int i = 0; i < 2; ++i) {
    int gr = row0 + r0 + i;
    if (gr < N) {
      float4 v0 = make_float4(acc[i][0], acc[i][1], acc[i][2], acc[i][3]);
      float4 v1 = make_float4(acc[i][4], acc[i][5], acc[i][6], acc[i][7]);
      *(float4*)(C + (size_t)gr * D + c0) = v0;
      *(float4*)(C + (size_t)gr * D + c0 + 4) = v1;
    }
  }
}

// ---------------- head: out[N,40] = H[N,128] @ W[128,40] + b ----------------
__global__ __launch_bounds__(640) void linhead(const float* __restrict__ H, const float* __restrict__ W,
                                               const float* __restrict__ bias, float* __restrict__ out, int N) {
  __shared__ float Ws[D * NCLS];
  __shared__ float Hs[16][D];
  const int tid = threadIdx.x;
  for (int i = tid; i < D * NCLS; i += 640) Ws[i] = W[i];
  const int row0 = blockIdx.x * 16;
  for (int i = tid; i < 16 * D; i += 640) {
    int r = i >> 7, c = i & (D - 1);
    int gr = row0 + r;
    Hs[r][c] = (gr < N) ? H[(size_t)gr * D + c] : 0.f;
  }
  __syncthreads();
  const int c = tid % NCLS;
  const int r = tid / NCLS;
  float acc = bias[c];
#pragma unroll 8
  for (int k = 0; k < D; ++k) acc += Hs[r][k] * Ws[k * NCLS + c];
  int gr = row0 + r;
  if (gr < N) out[(size_t)gr * NCLS + c] = acc;
}

extern "C" void kernel_launch(void* const* d_in, const int* in_sizes, int n_in,
                              void* d_out, int out_size, void* d_ws, size_t ws_size,
                              hipStream_t stream) {
  const float* x    = (const float*)d_in[0];
  const int*   ei   = (const int*)d_in[1];
  const float* W1   = (const float*)d_in[2];
  const float* b1   = (const float*)d_in[3];
  const float* W2   = (const float*)d_in[4];
  const float* b2   = (const float*)d_in[5];
  const float* Wlin = (const float*)d_in[6];
  const float* blin = (const float*)d_in[7];
  float* out = (float*)d_out;

  const int N = in_sizes[0] / D;   // 50000
  const int E = in_sizes[1] / 2;   // 600000
  const int* srcp = ei;
  const int* dstp = ei + E;

  // workspace layout
  char* ws = (char*)d_ws;
  float* dinv   = (float*)(ws);                  // 256 KB slot
  int*   rowptr = (int*)(ws + (size_t)262144);   // 256 KB slot (N+1 ints)
  int*   degcur = (int*)(ws + (size_t)524288);   // 256 KB slot (deg, then cursor)
  Edge*  csr    = (Edge*)(ws + (size_t)786432);  // E*8 = 4.8 MB
  float* t      = (float*)(ws + (size_t)6291456);            // 25.6 MB
  float* h      = (float*)(ws + (size_t)6291456 + 33554432); // 25.6 MB

  const int total = N * D;
  (void)total;
  dim3 b256(256);

  // CSR build
  hipMemsetAsync(degcur, 0, (size_t)N * sizeof(int), stream);
  deg_count_int<<<(E + 255) / 256, b256, 0, stream>>>(dstp, degcur, E);
  dinv_kernel<<<(N + 255) / 256, b256, 0, stream>>>(degcur, dinv, N);
  scan_rowptr<<<1, dim3(1024), 0, stream>>>(degcur, rowptr, N);
  hipMemcpyAsync(degcur, rowptr, (size_t)N * sizeof(int), hipMemcpyDeviceToDevice, stream);
  fill_csr<<<(E + 255) / 256, b256, 0, stream>>>(srcp, dstp, dinv, degcur, csr, E);

  // layer 1
  gemm128<<<(N + 31) / 32, b256, 0, stream>>>(x, W1, t, N);
  gather_fused<<<(N + 3) / 4, b256, 0, stream>>>(t, rowptr, csr, dinv, b1, h, N);

  // layer 2
  gemm128<<<(N + 31) / 32, b256, 0, stream>>>(h, W2, t, N);
  gather_fused<<<(N + 3) / 4, b256, 0, stream>>>(t, rowptr, csr, dinv, b2, h, N);

  // head
  linhead<<<(N + 15) / 16, dim3(640), 0, stream>>>(h, Wlin, blin, out, N);
}

// Round 3
// 268.985 us; speedup vs baseline: 2.9950x; 1.6859x over previous
//
#include <hip/hip_runtime.h>
#include <cmath>

#define D 128
#define NCLS 40

typedef __bf16 bfrag __attribute__((ext_vector_type(8)));
typedef float ffrag __attribute__((ext_vector_type(4)));
typedef unsigned short u16;
typedef unsigned int u32;

struct __align__(8) Edge { int s; float w; };

__device__ inline float bf2f(u32 u) {  // bf16 bits (low 16) -> fp32, exact
  union { float f; u32 u; } c; c.u = u << 16; return c.f;
}
__device__ inline u16 f2bf(float f) {  // fp32 -> bf16 RNE
  union { float f; u32 u; } c; c.f = f;
  u32 r = c.u + 0x7fffu + ((c.u >> 16) & 1u);
  return (u16)(r >> 16);
}

// ---------------- fp32 -> bf16 bulk convert (n % 4 == 0) ----------------
__global__ __launch_bounds__(256) void cvt_bf16(const float* __restrict__ src, u16* __restrict__ dst, int n) {
  int i = (blockIdx.x * 256 + threadIdx.x) * 4;
  if (i < n) {
    float4 v = *(const float4*)(src + i);
    ushort4 o;
    o.x = f2bf(v.x); o.y = f2bf(v.y); o.z = f2bf(v.z); o.w = f2bf(v.w);
    *(ushort4*)(dst + i) = o;
  }
}

// ---------------- degree / dinv ----------------
__global__ __launch_bounds__(256) void deg_count_int(const int* __restrict__ dst, int* __restrict__ deg, int E) {
  int e = blockIdx.x * 256 + threadIdx.x;
  if (e < E) atomicAdd(&deg[dst[e]], 1);
}

__global__ __launch_bounds__(256) void dinv_kernel(const int* __restrict__ deg, float* __restrict__ dinv, int n) {
  int i = blockIdx.x * 256 + threadIdx.x;
  if (i < n) dinv[i] = rsqrtf((float)deg[i] + 1.0f);  // +1 = self-loop
}

// ---------------- hierarchical exclusive scan (3 kernels) ----------------
__device__ inline int wave_incl_scan(int x, int lane) {
#pragma unroll
  for (int off = 1; off < 64; off <<= 1) {
    int y = __shfl_up(x, off, 64);
    if (lane >= off) x += y;
  }
  return x;
}

// per-block exclusive scan of 256 elems -> local (in rowptr), block total -> bsum
__global__ __launch_bounds__(256) void scan_block(const int* __restrict__ deg, int* __restrict__ local,
                                                  int* __restrict__ bsum, int n) {
  int i = blockIdx.x * 256 + threadIdx.x;
  int lane = threadIdx.x & 63, wid = threadIdx.x >> 6;
  int v = (i < n) ? deg[i] : 0;
  int x = wave_incl_scan(v, lane);
  __shared__ int ws4[4];
  if (lane == 63) ws4[wid] = x;
  __syncthreads();
  int wb = 0;
#pragma unroll
  for (int j = 0; j < 4; ++j) wb += (j < wid) ? ws4[j] : 0;
  if (i < n) local[i] = wb + x - v;
  if (threadIdx.x == 255) bsum[blockIdx.x] = wb + x;
}

// single-block exclusive scan of nb (<=256) block sums, in place
__global__ __launch_bounds__(256) void scan_bsum(int* __restrict__ bsum, int nb) {
  int i = threadIdx.x;
  int lane = threadIdx.x & 63, wid = threadIdx.x >> 6;
  int v = (i < nb) ? bsum[i] : 0;
  int x = wave_incl_scan(v, lane);
  __shared__ int ws4[4];
  if (lane == 63) ws4[wid] = x;
  __syncthreads();
  int wb = 0;
#pragma unroll
  for (int j = 0; j < 4; ++j) wb += (j < wid) ? ws4[j] : 0;
  if (i < nb) bsum[i] = wb + x - v;
}

__global__ __launch_bounds__(256) void scan_add(int* __restrict__ rowptr, const int* __restrict__ bsum,
                                                int n, int E) {
  int i = blockIdx.x * 256 + threadIdx.x;
  if (i < n) rowptr[i] += bsum[blockIdx.x];
  if (i == 0) rowptr[n] = E;
}

// ---------------- CSR fill ----------------
__global__ __launch_bounds__(256) void fill_csr(const int* __restrict__ src, const int* __restrict__ dst,
                                                const float* __restrict__ dinv, int* __restrict__ cursor,
                                                Edge* __restrict__ csr, int E) {
  int e = blockIdx.x * 256 + threadIdx.x;
  if (e < E) {
    int s = src[e], d = dst[e];
    int pos = atomicAdd(&cursor[d], 1);
    Edge ed; ed.s = s; ed.w = dinv[s] * dinv[d];
    csr[pos] = ed;
  }
}

// ---------------- fused propagate (bf16 in/out, fp32 accumulate) ----------------
// out[i,:] = tanh( dinv[i]^2 * t[i,:] + sum_e w_e * t[src_e,:] + b )
__global__ __launch_bounds__(256) void gather_bf16(const u16* __restrict__ t, const int* __restrict__ row_ptr,
                                                   const Edge* __restrict__ csr, const float* __restrict__ dinv,
                                                   const float* __restrict__ bias, u16* __restrict__ out, int N) {
  int node = blockIdx.x * 4 + (threadIdx.x >> 6);
  if (node >= N) return;
  int lane = threadIdx.x & 63;
  float dv = dinv[node];
  u32 tv = *(const u32*)(t + (size_t)node * D + lane * 2);
  float ax = dv * dv * bf2f(tv & 0xffffu);
  float ay = dv * dv * bf2f(tv >> 16);
  int e = row_ptr[node], end = row_ptr[node + 1];
  // unroll-by-4: batch edge loads then batch row loads -> 4 loads in flight
  for (; e + 4 <= end; e += 4) {
    Edge e0 = csr[e], e1 = csr[e + 1], e2 = csr[e + 2], e3 = csr[e + 3];
    u32 r0 = *(const u32*)(t + (size_t)e0.s * D + lane * 2);
    u32 r1 = *(const u32*)(t + (size_t)e1.s * D + lane * 2);
    u32 r2 = *(const u32*)(t + (size_t)e2.s * D + lane * 2);
    u32 r3 = *(const u32*)(t + (size_t)e3.s * D + lane * 2);
    ax += e0.w * bf2f(r0 & 0xffffu); ay += e0.w * bf2f(r0 >> 16);
    ax += e1.w * bf2f(r1 & 0xffffu); ay += e1.w * bf2f(r1 >> 16);
    ax += e2.w * bf2f(r2 & 0xffffu); ay += e2.w * bf2f(r2 >> 16);
    ax += e3.w * bf2f(r3 & 0xffffu); ay += e3.w * bf2f(r3 >> 16);
  }
  for (; e < end; ++e) {
    Edge ed = csr[e];
    u32 r = *(const u32*)(t + (size_t)ed.s * D + lane * 2);
    ax += ed.w * bf2f(r & 0xffffu); ay += ed.w * bf2f(r >> 16);
  }
  float2 bv = *(const float2*)(bias + lane * 2);
  ax = tanhf(ax + bv.x);
  ay = tanhf(ay + bv.y);
  u32 o = ((u32)f2bf(ay) << 16) | (u32)f2bf(ax);
  *(u32*)(out + (size_t)node * D + lane * 2) = o;
}

// ---------------- MFMA GEMM: C[N,128] = A[N,128] @ B[128,128] ----------------
// A,C bf16 storage; B fp32 global, converted+transposed into LDS (k-major rows).
__global__ __launch_bounds__(256) void gemm_bf16(const u16* __restrict__ A, const float* __restrict__ B,
                                                 u16* __restrict__ C, int N) {
  __shared__ __align__(16) u16 Bs[128][136];  // Bs[n][k], padded to 136 (272B rows, 16B-aligned)
  const int tid = threadIdx.x;
  const int wave = tid >> 6, lane = tid & 63;
  const int row0 = blockIdx.x * 64 + wave * 16;

  // A fragments straight from global (A-operand: m = lane&15, k = (lane>>4)*8 + j)
  int arow = row0 + (lane & 15);
  int rclamp = arow < N ? arow : N - 1;
  const int koff = (lane >> 4) * 8;
  bfrag a[4];
#pragma unroll
  for (int kk = 0; kk < 4; ++kk)
    a[kk] = *(const bfrag*)(A + (size_t)rclamp * D + kk * 32 + koff);

  // stage B transposed: Bs[n][k] = bf16(B[k][n])
  for (int i = tid; i < D * D; i += 256) {
    int k = i >> 7, n = i & 127;
    Bs[n][k] = f2bf(B[i]);
  }
  __syncthreads();

  ffrag acc[8];
#pragma unroll
  for (int tile = 0; tile < 8; ++tile) acc[tile] = (ffrag){0.f, 0.f, 0.f, 0.f};

#pragma unroll
  for (int kk = 0; kk < 4; ++kk) {
#pragma unroll
    for (int tile = 0; tile < 8; ++tile) {
      bfrag b = *(const bfrag*)(&Bs[tile * 16 + (lane & 15)][kk * 32 + koff]);
      acc[tile] = __builtin_amdgcn_mfma_f32_16x16x32_bf16(a[kk], b, acc[tile], 0, 0, 0);
    }
  }

  // C/D layout: col = lane&15, row = (lane>>4)*4 + i
  int orow0 = row0 + (lane >> 4) * 4;
  int ocol = lane & 15;
#pragma unroll
  for (int tile = 0; tile < 8; ++tile) {
#pragma unroll
    for (int i = 0; i < 4; ++i) {
      int r = orow0 + i;
      if (r < N) C[(size_t)r * D + tile * 16 + ocol] = f2bf(acc[tile][i]);
    }
  }
}

// ---------------- MFMA head: out[N,40] = H[N,128] @ W[128,40] + b ----------------
__global__ __launch_bounds__(256) void head_bf16(const u16* __restrict__ H, const float* __restrict__ W,
                                                 const float* __restrict__ bias, float* __restrict__ out, int N) {
  __shared__ __align__(16) u16 Ws[48][136];  // cols padded 40 -> 48
  const int tid = threadIdx.x;
  const int wave = tid >> 6, lane = tid & 63;
  const int row0 = blockIdx.x * 64 + wave * 16;

  int arow = row0 + (lane & 15);
  int rclamp = arow < N ? arow : N - 1;
  const int koff = (lane >> 4) * 8;
  bfrag a[4];
#pragma unroll
  for (int kk = 0; kk < 4; ++kk)
    a[kk] = *(const bfrag*)(H + (size_t)rclamp * D + kk * 32 + koff);

  for (int i = tid; i < 48 * D; i += 256) {
    int n = i >> 7, k = i & 127;
    Ws[n][k] = (n < NCLS) ? f2bf(W[k * NCLS + n]) : (u16)0;
  }
  __syncthreads();

  ffrag acc[3];
#pragma unroll
  for (int tile = 0; tile < 3; ++tile) acc[tile] = (ffrag){0.f, 0.f, 0.f, 0.f};

#pragma unroll
  for (int kk = 0; kk < 4; ++kk) {
#pragma unroll
    for (int tile = 0; tile < 3; ++tile) {
      bfrag b = *(const bfrag*)(&Ws[tile * 16 + (lane & 15)][kk * 32 + koff]);
      acc[tile] = __builtin_amdgcn_mfma_f32_16x16x32_bf16(a[kk], b, acc[tile], 0, 0, 0);
    }
  }

  int orow0 = row0 + (lane >> 4) * 4;
  int ocol = lane & 15;
#pragma unroll
  for (int tile = 0; tile < 3; ++tile) {
    int c = tile * 16 + ocol;
    if (c < NCLS) {
#pragma unroll
      for (int i = 0; i < 4; ++i) {
        int r = orow0 + i;
        if (r < N) out[(size_t)r * NCLS + c] = acc[tile][i] + bias[c];
      }
    }
  }
}

extern "C" void kernel_launch(void* const* d_in, const int* in_sizes, int n_in,
                              void* d_out, int out_size, void* d_ws, size_t ws_size,
                              hipStream_t stream) {
  const float* x    = (const float*)d_in[0];
  const int*   ei   = (const int*)d_in[1];
  const float* W1   = (const float*)d_in[2];
  const float* b1   = (const float*)d_in[3];
  const float* W2   = (const float*)d_in[4];
  const float* b2   = (const float*)d_in[5];
  const float* Wlin = (const float*)d_in[6];
  const float* blin = (const float*)d_in[7];
  float* out = (float*)d_out;

  const int N = in_sizes[0] / D;   // 50000
  const int E = in_sizes[1] / 2;   // 600000
  const int* srcp = ei;
  const int* dstp = ei + E;

  // workspace layout (total ~53 MB)
  char* ws = (char*)d_ws;
  float* dinv   = (float*)(ws);                         // 256 KB slot
  int*   rowptr = (int*)(ws + (size_t)262144);          // 256 KB slot (N+1)
  int*   degcur = (int*)(ws + (size_t)524288);          // 256 KB slot
  int*   bsum   = (int*)(ws + (size_t)786432);          // 4 KB slot
  Edge*  csr    = (Edge*)(ws + (size_t)1048576);        // 4.8 MB
  u16*   xb     = (u16*)(ws + (size_t)8388608);         // 12.8 MB
  u16*   tb     = (u16*)(ws + (size_t)25165824);        // 12.8 MB
  u16*   hb     = (u16*)(ws + (size_t)41943040);        // 12.8 MB

  const int total = N * D;
  const int nb = (N + 255) / 256;  // 196 scan blocks
  dim3 b256(256);

  // x -> bf16
  cvt_bf16<<<(total / 4 + 255) / 256, b256, 0, stream>>>(x, xb, total);

  // CSR build
  hipMemsetAsync(degcur, 0, (size_t)N * sizeof(int), stream);
  deg_count_int<<<(E + 255) / 256, b256, 0, stream>>>(dstp, degcur, E);
  dinv_kernel<<<(N + 255) / 256, b256, 0, stream>>>(degcur, dinv, N);
  scan_block<<<nb, b256, 0, stream>>>(degcur, rowptr, bsum, N);
  scan_bsum<<<1, b256, 0, stream>>>(bsum, nb);
  scan_add<<<nb, b256, 0, stream>>>(rowptr, bsum, N, E);
  hipMemcpyAsync(degcur, rowptr, (size_t)N * sizeof(int), hipMemcpyDeviceToDevice, stream);
  fill_csr<<<(E + 255) / 256, b256, 0, stream>>>(srcp, dstp, dinv, degcur, csr, E);

  const int gemm_grid = (N + 63) / 64;

  // layer 1
  gemm_bf16<<<gemm_grid, b256, 0, stream>>>(xb, W1, tb, N);
  gather_bf16<<<(N + 3) / 4, b256, 0, stream>>>(tb, rowptr, csr, dinv, b1, hb, N);

  // layer 2
  gemm_bf16<<<gemm_grid, b256, 0, stream>>>(hb, W2, tb, N);
  gather_bf16<<<(N + 3) / 4, b256, 0, stream>>>(tb, rowptr, csr, dinv, b2, hb, N);

  // head
  head_bf16<<<gemm_grid, b256, 0, stream>>>(hb, Wlin, blin, out, N);
}

// Round 4
// 237.406 us; speedup vs baseline: 3.3934x; 1.1330x over previous
//
#include <hip/hip_runtime.h>
#include <cmath>

#define D 128
#define NCLS 40

typedef __bf16 bfrag __attribute__((ext_vector_type(8)));
typedef __bf16 bf2 __attribute__((ext_vector_type(2)));
typedef float ffrag __attribute__((ext_vector_type(4)));
typedef unsigned short u16;
typedef unsigned int u32;

struct __align__(8) Edge { int s; float w; };

// ---------------- weights -> bf16, transposed [n][k] ----------------
__global__ __launch_bounds__(256) void cvt_weights(const float* __restrict__ W1, const float* __restrict__ W2,
                                                   const float* __restrict__ Wl, __bf16* __restrict__ Wt1,
                                                   __bf16* __restrict__ Wt2, __bf16* __restrict__ Wlt) {
  int i = blockIdx.x * 256 + threadIdx.x;
  if (i < 16384) {
    int n = i >> 7, k = i & 127;
    Wt1[i] = (__bf16)W1[k * D + n];
  } else if (i < 32768) {
    int j = i - 16384;
    int n = j >> 7, k = j & 127;
    Wt2[j] = (__bf16)W2[k * D + n];
  } else if (i < 32768 + 48 * D) {
    int j = i - 32768;
    int n = j >> 7, k = j & 127;
    Wlt[j] = (n < NCLS) ? (__bf16)Wl[k * NCLS + n] : (__bf16)0.0f;
  }
}

// ---------------- degree ----------------
__global__ __launch_bounds__(256) void deg_count_int(const int* __restrict__ dst, int* __restrict__ deg, int E) {
  int e = blockIdx.x * 256 + threadIdx.x;
  if (e < E) atomicAdd(&deg[dst[e]], 1);
}

// ---------------- hierarchical scan (3 kernels), dinv fused into pass 1 ----------------
__device__ inline int wave_incl_scan(int x, int lane) {
#pragma unroll
  for (int off = 1; off < 64; off <<= 1) {
    int y = __shfl_up(x, off, 64);
    if (lane >= off) x += y;
  }
  return x;
}

__global__ __launch_bounds__(256) void scan_block(const int* __restrict__ deg, float* __restrict__ dinv,
                                                  int* __restrict__ local, int* __restrict__ bsum, int n) {
  int i = blockIdx.x * 256 + threadIdx.x;
  int lane = threadIdx.x & 63, wid = threadIdx.x >> 6;
  int v = (i < n) ? deg[i] : 0;
  if (i < n) dinv[i] = rsqrtf((float)v + 1.0f);  // +1 = self-loop
  int x = wave_incl_scan(v, lane);
  __shared__ int ws4[4];
  if (lane == 63) ws4[wid] = x;
  __syncthreads();
  int wb = 0;
#pragma unroll
  for (int j = 0; j < 4; ++j) wb += (j < wid) ? ws4[j] : 0;
  if (i < n) local[i] = wb + x - v;
  if (threadIdx.x == 255) bsum[blockIdx.x] = wb + x;
}

__global__ __launch_bounds__(256) void scan_bsum(int* __restrict__ bsum, int nb) {
  int i = threadIdx.x;
  int lane = threadIdx.x & 63, wid = threadIdx.x >> 6;
  int v = (i < nb) ? bsum[i] : 0;
  int x = wave_incl_scan(v, lane);
  __shared__ int ws4[4];
  if (lane == 63) ws4[wid] = x;
  __syncthreads();
  int wb = 0;
#pragma unroll
  for (int j = 0; j < 4; ++j) wb += (j < wid) ? ws4[j] : 0;
  if (i < nb) bsum[i] = wb + x - v;
}

// adds block offsets; also writes the cursor copy for fill_csr (saves a memcpy)
__global__ __launch_bounds__(256) void scan_add(int* __restrict__ rowptr, int* __restrict__ cursor,
                                                const int* __restrict__ bsum, int n, int E) {
  int i = blockIdx.x * 256 + threadIdx.x;
  if (i < n) {
    int r = rowptr[i] + bsum[blockIdx.x];
    rowptr[i] = r;
    cursor[i] = r;
  }
  if (i == 0) rowptr[n] = E;
}

// ---------------- CSR fill ----------------
__global__ __launch_bounds__(256) void fill_csr(const int* __restrict__ src, const int* __restrict__ dst,
                                                const float* __restrict__ dinv, int* __restrict__ cursor,
                                                Edge* __restrict__ csr, int E) {
  int e = blockIdx.x * 256 + threadIdx.x;
  if (e < E) {
    int s = src[e], d = dst[e];
    int pos = atomicAdd(&cursor[d], 1);
    Edge ed; ed.s = s; ed.w = dinv[s] * dinv[d];
    csr[pos] = ed;
  }
}

// ---------------- fused propagate (bf16 in/out, fp32 accumulate) ----------------
__global__ __launch_bounds__(256) void gather_bf16(const __bf16* __restrict__ t, const int* __restrict__ row_ptr,
                                                   const Edge* __restrict__ csr, const float* __restrict__ dinv,
                                                   const float* __restrict__ bias, __bf16* __restrict__ out, int N) {
  int node = blockIdx.x * 4 + (threadIdx.x >> 6);
  if (node >= N) return;
  int lane = threadIdx.x & 63;
  float dv = dinv[node];
  bf2 tv = *(const bf2*)(t + (size_t)node * D + lane * 2);
  float ax = dv * dv * (float)tv[0];
  float ay = dv * dv * (float)tv[1];
  int e = __builtin_amdgcn_readfirstlane(row_ptr[node]);
  int end = __builtin_amdgcn_readfirstlane(row_ptr[node + 1]);
  for (; e + 4 <= end; e += 4) {
    Edge e0 = csr[e], e1 = csr[e + 1], e2 = csr[e + 2], e3 = csr[e + 3];
    bf2 r0 = *(const bf2*)(t + (size_t)e0.s * D + lane * 2);
    bf2 r1 = *(const bf2*)(t + (size_t)e1.s * D + lane * 2);
    bf2 r2 = *(const bf2*)(t + (size_t)e2.s * D + lane * 2);
    bf2 r3 = *(const bf2*)(t + (size_t)e3.s * D + lane * 2);
    ax += e0.w * (float)r0[0]; ay += e0.w * (float)r0[1];
    ax += e1.w * (float)r1[0]; ay += e1.w * (float)r1[1];
    ax += e2.w * (float)r2[0]; ay += e2.w * (float)r2[1];
    ax += e3.w * (float)r3[0]; ay += e3.w * (float)r3[1];
  }
  for (; e < end; ++e) {
    Edge ed = csr[e];
    bf2 r = *(const bf2*)(t + (size_t)ed.s * D + lane * 2);
    ax += ed.w * (float)r[0]; ay += ed.w * (float)r[1];
  }
  float2 bv = *(const float2*)(bias + lane * 2);
  bf2 o;
  o[0] = (__bf16)tanhf(ax + bv.x);
  o[1] = (__bf16)tanhf(ay + bv.y);
  __builtin_nontemporal_store(*(u32*)&o, (u32*)(out + (size_t)node * D + lane * 2));
}

// ---------------- MFMA GEMM: C[N,128] = A[N,128] @ B[128,128] ----------------
// Wt: pre-converted bf16, transposed [n][k]. 128 rows/block, 4 waves x 2 m-tiles.
template <typename AT>
__global__ __launch_bounds__(256) void gemm_mfma(const AT* __restrict__ A, const __bf16* __restrict__ Wt,
                                                 __bf16* __restrict__ C, int N) {
  __shared__ __align__(16) __bf16 Bs[128][136];
  const int tid = threadIdx.x;
  const int wave = tid >> 6, lane = tid & 63;
  const int row0 = blockIdx.x * 128 + wave * 32;
  const int koff = (lane >> 4) * 8;

  // stage Wt -> LDS (16B vector copies)
  for (int i = tid; i < 128 * 16; i += 256) {
    int n = i >> 4, seg = i & 15;
    *(uint4*)&Bs[n][seg * 8] = *(const uint4*)(Wt + n * D + seg * 8);
  }

  // A fragments: 2 m-tiles of 16 rows
  bfrag a[2][4];
#pragma unroll
  for (int mt = 0; mt < 2; ++mt) {
    int r = row0 + mt * 16 + (lane & 15);
    int rc = r < N ? r : N - 1;
    const AT* p = A + (size_t)rc * D;
#pragma unroll
    for (int kk = 0; kk < 4; ++kk) {
      if constexpr (sizeof(AT) == 4) {  // fp32 A: load + convert in-register
        float4 u = *(const float4*)(p + kk * 32 + koff);
        float4 v = *(const float4*)(p + kk * 32 + koff + 4);
        bfrag f;
        f[0] = (__bf16)u.x; f[1] = (__bf16)u.y; f[2] = (__bf16)u.z; f[3] = (__bf16)u.w;
        f[4] = (__bf16)v.x; f[5] = (__bf16)v.y; f[6] = (__bf16)v.z; f[7] = (__bf16)v.w;
        a[mt][kk] = f;
      } else {
        a[mt][kk] = *(const bfrag*)(p + kk * 32 + koff);
      }
    }
  }
  __syncthreads();

  ffrag acc[2][8];
#pragma unroll
  for (int mt = 0; mt < 2; ++mt)
#pragma unroll
    for (int n = 0; n < 8; ++n) acc[mt][n] = (ffrag){0.f, 0.f, 0.f, 0.f};

#pragma unroll
  for (int kk = 0; kk < 4; ++kk) {
#pragma unroll
    for (int n = 0; n < 8; ++n) {
      bfrag b = *(const bfrag*)(&Bs[n * 16 + (lane & 15)][kk * 32 + koff]);
      acc[0][n] = __builtin_amdgcn_mfma_f32_16x16x32_bf16(a[0][kk], b, acc[0][n], 0, 0, 0);
      acc[1][n] = __builtin_amdgcn_mfma_f32_16x16x32_bf16(a[1][kk], b, acc[1][n], 0, 0, 0);
    }
  }

  // C/D layout: col = lane&15, row = (lane>>4)*4 + i
  int ocol = lane & 15;
#pragma unroll
  for (int mt = 0; mt < 2; ++mt) {
    int orow0 = row0 + mt * 16 + (lane >> 4) * 4;
#pragma unroll
    for (int n = 0; n < 8; ++n)
#pragma unroll
      for (int i = 0; i < 4; ++i) {
        int r = orow0 + i;
        if (r < N) C[(size_t)r * D + n * 16 + ocol] = (__bf16)acc[mt][n][i];
      }
  }
}

// ---------------- MFMA head: out[N,40] = H[N,128] @ Wlt^T + b ----------------
__global__ __launch_bounds__(256) void head_mfma(const __bf16* __restrict__ H, const __bf16* __restrict__ Wlt,
                                                 const float* __restrict__ bias, float* __restrict__ out, int N) {
  __shared__ __align__(16) __bf16 Ws[48][136];
  const int tid = threadIdx.x;
  const int wave = tid >> 6, lane = tid & 63;
  const int row0 = blockIdx.x * 128 + wave * 32;
  const int koff = (lane >> 4) * 8;

  for (int i = tid; i < 48 * 16; i += 256) {
    int n = i >> 4, seg = i & 15;
    *(uint4*)&Ws[n][seg * 8] = *(const uint4*)(Wlt + n * D + seg * 8);
  }

  bfrag a[2][4];
#pragma unroll
  for (int mt = 0; mt < 2; ++mt) {
    int r = row0 + mt * 16 + (lane & 15);
    int rc = r < N ? r : N - 1;
#pragma unroll
    for (int kk = 0; kk < 4; ++kk)
      a[mt][kk] = *(const bfrag*)(H + (size_t)rc * D + kk * 32 + koff);
  }
  __syncthreads();

  ffrag acc[2][3];
#pragma unroll
  for (int mt = 0; mt < 2; ++mt)
#pragma unroll
    for (int n = 0; n < 3; ++n) acc[mt][n] = (ffrag){0.f, 0.f, 0.f, 0.f};

#pragma unroll
  for (int kk = 0; kk < 4; ++kk) {
#pragma unroll
    for (int n = 0; n < 3; ++n) {
      bfrag b = *(const bfrag*)(&Ws[n * 16 + (lane & 15)][kk * 32 + koff]);
      acc[0][n] = __builtin_amdgcn_mfma_f32_16x16x32_bf16(a[0][kk], b, acc[0][n], 0, 0, 0);
      acc[1][n] = __builtin_amdgcn_mfma_f32_16x16x32_bf16(a[1][kk], b, acc[1][n], 0, 0, 0);
    }
  }

  int ocol = lane & 15;
#pragma unroll
  for (int mt = 0; mt < 2; ++mt) {
    int orow0 = row0 + mt * 16 + (lane >> 4) * 4;
#pragma unroll
    for (int n = 0; n < 3; ++n) {
      int c = n * 16 + ocol;
      if (c < NCLS) {
#pragma unroll
        for (int i = 0; i < 4; ++i) {
          int r = orow0 + i;
          if (r < N) out[(size_t)r * NCLS + c] = acc[mt][n][i] + bias[c];
        }
      }
    }
  }
}

extern "C" void kernel_launch(void* const* d_in, const int* in_sizes, int n_in,
                              void* d_out, int out_size, void* d_ws, size_t ws_size,
                              hipStream_t stream) {
  const float* x    = (const float*)d_in[0];
  const int*   ei   = (const int*)d_in[1];
  const float* W1   = (const float*)d_in[2];
  const float* b1   = (const float*)d_in[3];
  const float* W2   = (const float*)d_in[4];
  const float* b2   = (const float*)d_in[5];
  const float* Wlin = (const float*)d_in[6];
  const float* blin = (const float*)d_in[7];
  float* out = (float*)d_out;

  const int N = in_sizes[0] / D;   // 50000
  const int E = in_sizes[1] / 2;   // 600000
  const int* srcp = ei;
  const int* dstp = ei + E;

  // workspace layout (~38 MB)
  char* ws = (char*)d_ws;
  float*  dinv   = (float*)(ws);                     // 200 KB
  int*    rowptr = (int*)(ws + (size_t)262144);      // N+1 ints
  int*    cursor = (int*)(ws + (size_t)524288);
  int*    bsum   = (int*)(ws + (size_t)786432);      // 196 ints
  __bf16* Wt1    = (__bf16*)(ws + (size_t)790528);   // 32 KB
  __bf16* Wt2    = (__bf16*)(ws + (size_t)823296);   // 32 KB
  __bf16* Wlt    = (__bf16*)(ws + (size_t)856064);   // 12.3 KB
  Edge*   csr    = (Edge*)(ws + (size_t)1048576);    // 4.8 MB
  __bf16* tb     = (__bf16*)(ws + (size_t)8388608);  // 12.8 MB
  __bf16* hb     = (__bf16*)(ws + (size_t)25165824); // 12.8 MB

  const int nb = (N + 255) / 256;  // 196
  dim3 b256(256);

  // weights -> bf16 transposed (independent of everything else)
  cvt_weights<<<152, b256, 0, stream>>>(W1, W2, Wlin, Wt1, Wt2, Wlt);

  // CSR build (6 dispatches)
  hipMemsetAsync(cursor, 0, (size_t)N * sizeof(int), stream);
  deg_count_int<<<(E + 255) / 256, b256, 0, stream>>>(dstp, cursor, E);
  scan_block<<<nb, b256, 0, stream>>>(cursor, dinv, rowptr, bsum, N);
  scan_bsum<<<1, b256, 0, stream>>>(bsum, nb);
  scan_add<<<nb, b256, 0, stream>>>(rowptr, cursor, bsum, N, E);
  fill_csr<<<(E + 255) / 256, b256, 0, stream>>>(srcp, dstp, dinv, cursor, csr, E);

  const int gg = (N + 127) / 128;  // 391

  // layer 1 (A = fp32 x, converted in-register)
  gemm_mfma<float><<<gg, b256, 0, stream>>>(x, Wt1, tb, N);
  gather_bf16<<<(N + 3) / 4, b256, 0, stream>>>(tb, rowptr, csr, dinv, b1, hb, N);

  // layer 2
  gemm_mfma<__bf16><<<gg, b256, 0, stream>>>(hb, Wt2, tb, N);
  gather_bf16<<<(N + 3) / 4, b256, 0, stream>>>(tb, rowptr, csr, dinv, b2, hb, N);

  // head
  head_mfma<<<gg, b256, 0, stream>>>(hb, Wlt, blin, out, N);
}